// Round 9
// baseline (628.320 us; speedup 1.0000x reference)
//
#include <hip/hip_runtime.h>

#define SEQ 768
#define PRED 192
#define ENC 321
#define NB 2
#define BE (NB*ENC)

typedef float vf2 __attribute__((ext_vector_type(2)));

union F4V2 { float4 f4; vf2 v2[2]; };

__device__ __forceinline__ float4 ldg4(const float* p) {
    return *reinterpret_cast<const float4*>(p);
}
__device__ __forceinline__ float2 ldg2(const float* p) {
    return *reinterpret_cast<const float2*>(p);
}
// packed fp32 FMA with op_sel broadcast of a.lo / a.hi (half-rate but halves issue slots)
__device__ __forceinline__ void pklo(vf2& c, vf2 a, vf2 b) {
    asm("v_pk_fma_f32 %0, %1, %2, %0 op_sel:[0,0,0] op_sel_hi:[0,1,1]"
        : "+v"(c) : "v"(a), "v"(b));
}
__device__ __forceinline__ void pkhi(vf2& c, vf2 a, vf2 b) {
    asm("v_pk_fma_f32 %0, %1, %2, %0 op_sel:[1,0,0] op_sel_hi:[1,1,1]"
        : "+v"(c) : "v"(a), "v"(b));
}

__host__ __device__ __forceinline__ int d_Lw(int s)    { return s==0?192:(s==1?384:768); }
__host__ __device__ __forceinline__ int d_Hoff(int s)  { return s==0?0:(s==1?49152:147456); }
__host__ __device__ __forceinline__ int d_twoff(int s) { return s==0?0:(s==1?6144:18432); }

// ------------------------------------------------------------------
__global__ void k_stats(const float* __restrict__ hist,
                        float* __restrict__ meanb, float* __restrict__ stdb) {
    int j  = blockIdx.x*64 + threadIdx.x;
    int b  = blockIdx.y;
    int ty = threadIdx.y;
    float s = 0.f, s2 = 0.f;
    if (j < ENC) {
        for (int t = ty; t < SEQ; t += 4) {
            float v = hist[(size_t)b*SEQ*ENC + (size_t)t*ENC + j];
            s += v; s2 += v*v;
        }
    }
    __shared__ float l1[4][64], l2[4][64];
    l1[ty][threadIdx.x] = s; l2[ty][threadIdx.x] = s2;
    __syncthreads();
    if (ty == 0 && j < ENC) {
        float S  = l1[0][threadIdx.x]+l1[1][threadIdx.x]+l1[2][threadIdx.x]+l1[3][threadIdx.x];
        float S2 = l2[0][threadIdx.x]+l2[1][threadIdx.x]+l2[2][threadIdx.x]+l2[3][threadIdx.x];
        float m   = S * (1.f/SEQ);
        float var = S2 * (1.f/SEQ) - m*m;
        meanb[b*ENC+j] = m;
        stdb[b*ENC+j]  = sqrtf(var + 1e-5f);
    }
}

__global__ void k_norm(const float* __restrict__ hist,
                       const float* __restrict__ meanb, const float* __restrict__ stdb,
                       const float* __restrict__ aw, const float* __restrict__ ab,
                       float* __restrict__ xn) {
    int i = blockIdx.x*256 + threadIdx.x;
    if (i >= NB*SEQ*ENC) return;
    int j = i % ENC;
    int b = i / (SEQ*ENC);
    float v = (hist[i] - meanb[b*ENC+j]) / stdb[b*ENC+j];
    xn[i] = v * aw[j] + ab[j];
}

// twm[s][m][k] = e^{-2pi i k m / Lw};  gtm[s][r][k] = kappa_k e^{+2pi i k (191-r)/Lw}
__global__ void k_tw(float2* __restrict__ twm, float2* __restrict__ gtm) {
    int i = blockIdx.x*256 + threadIdx.x;
    if (i >= 43008) return;
    int s, rem;
    if (i < 6144)       { s=0; rem=i; }
    else if (i < 18432) { s=1; rem=i-6144; }
    else                { s=2; rem=i-18432; }
    int Lw = d_Lw(s);
    int k = rem & 31, m = rem >> 5;
    const float TWO_PI = 6.28318530717958647692f;
    int km = (k*m) % Lw;
    float c, sn;
    sincosf(TWO_PI * km / Lw, &sn, &c);
    twm[i] = make_float2(c, -sn);
    int e = (k*(PRED-1-m)) % Lw; if (e < 0) e += Lw;
    float c2, s2v;
    sincosf(TWO_PI * e / Lw, &s2v, &c2);
    float coef = (k==0 ? 1.f : 2.f) / (float)Lw;
    gtm[i] = make_float2(coef*c2, coef*s2v);
}

__global__ void k_hinit(const float* __restrict__ Ast, const float* __restrict__ Bst,
                        float* __restrict__ apow, float* __restrict__ Hbuf) {
    int i = blockIdx.x*256 + threadIdx.x;
    if (i < 3*65536) apow[i] = Ast[i];
    if (i < 3*256) {
        int s = i >> 8, n = i & 255;
        Hbuf[d_Hoff(s) + n] = Bst[i];
    }
}

// ---------- 64x64 tile GEMM cores (pk-fma asm + register prefetch) ----------
// NT: C[m,n] = sum_q A[m,q]*B[n,q]
__device__ __forceinline__ void gemm64nt(
    const float* __restrict__ A, int lda, int Arows,
    const float* __restrict__ B, int ldb,
    float* __restrict__ C, int ldc, int m0, int n0, int K)
{
    __shared__ __align__(16) float AsT[16][68];
    __shared__ __align__(16) float BsT[16][68];
    int tid = threadIdx.x;
    int tm = tid >> 4, tn = tid & 15;
    int lr = tid >> 2, lq = (tid & 3)*4;
    bool aok = (m0 + lr) < Arows;
    const float* Ap = A + (size_t)(m0+lr)*lda + lq;
    const float* Bp = B + (size_t)(n0+lr)*ldb + lq;
    float4 fa = aok ? ldg4(Ap) : make_float4(0.f,0.f,0.f,0.f);
    float4 fb = ldg4(Bp);
    vf2 acc[4][2] = {};
    for (int kt = 0; kt < K; kt += 16) {
        __syncthreads();
        AsT[lq+0][lr]=fa.x; AsT[lq+1][lr]=fa.y; AsT[lq+2][lr]=fa.z; AsT[lq+3][lr]=fa.w;
        BsT[lq+0][lr]=fb.x; BsT[lq+1][lr]=fb.y; BsT[lq+2][lr]=fb.z; BsT[lq+3][lr]=fb.w;
        __syncthreads();
        if (kt + 16 < K) {
            fa = aok ? ldg4(Ap + kt + 16) : make_float4(0.f,0.f,0.f,0.f);
            fb = ldg4(Bp + kt + 16);
        }
        #pragma unroll
        for (int q = 0; q < 16; q++) {
            F4V2 ua, ub;
            ua.f4 = *reinterpret_cast<float4*>(&AsT[q][tm*4]);
            ub.f4 = *reinterpret_cast<float4*>(&BsT[q][tn*4]);
            #pragma unroll
            for (int ra = 0; ra < 2; ra++)
                #pragma unroll
                for (int cp = 0; cp < 2; cp++) {
                    pklo(acc[2*ra+0][cp], ua.v2[ra], ub.v2[cp]);
                    pkhi(acc[2*ra+1][cp], ua.v2[ra], ub.v2[cp]);
                }
        }
    }
    #pragma unroll
    for (int r = 0; r < 4; r++) {
        int m = m0 + tm*4 + r; if (m >= Arows) continue;
        float4 o4 = make_float4(acc[r][0].x, acc[r][0].y, acc[r][1].x, acc[r][1].y);
        *reinterpret_cast<float4*>(C + (size_t)m*ldc + n0 + tn*4) = o4;
    }
}

// NN: C[m,n] = sum_q A[m,q]*B[q,n]
__device__ __forceinline__ void gemm64nn(
    const float* __restrict__ A, int lda,
    const float* __restrict__ B, int ldb,
    float* __restrict__ C, int ldc, int m0, int n0, int K)
{
    __shared__ __align__(16) float AsT[16][68];
    __shared__ __align__(16) float Bs[16][68];
    int tid = threadIdx.x;
    int tm = tid >> 4, tn = tid & 15;
    int lr = tid >> 2, lq = (tid & 3)*4;
    int blq = tid >> 4, blc = (tid & 15)*4;
    const float* Ap = A + (size_t)(m0+lr)*lda + lq;
    const float* Bp = B + (size_t)blq*ldb + n0 + blc;
    float4 fa = ldg4(Ap);
    float4 fb = ldg4(Bp);
    vf2 acc[4][2] = {};
    for (int kt = 0; kt < K; kt += 16) {
        __syncthreads();
        AsT[lq+0][lr]=fa.x; AsT[lq+1][lr]=fa.y; AsT[lq+2][lr]=fa.z; AsT[lq+3][lr]=fa.w;
        *reinterpret_cast<float4*>(&Bs[blq][blc]) = fb;
        __syncthreads();
        if (kt + 16 < K) {
            fa = ldg4(Ap + kt + 16);
            fb = ldg4(Bp + (size_t)(kt+16)*ldb);
        }
        #pragma unroll
        for (int q = 0; q < 16; q++) {
            F4V2 ua, ub;
            ua.f4 = *reinterpret_cast<float4*>(&AsT[q][tm*4]);
            ub.f4 = *reinterpret_cast<float4*>(&Bs[q][tn*4]);
            #pragma unroll
            for (int ra = 0; ra < 2; ra++)
                #pragma unroll
                for (int cp = 0; cp < 2; cp++) {
                    pklo(acc[2*ra+0][cp], ua.v2[ra], ub.v2[cp]);
                    pkhi(acc[2*ra+1][cp], ua.v2[ra], ub.v2[cp]);
                }
        }
    }
    #pragma unroll
    for (int r = 0; r < 4; r++) {
        int m = m0 + tm*4 + r;
        float4 o4 = make_float4(acc[r][0].x, acc[r][0].y, acc[r][1].x, acc[r][1].y);
        *reinterpret_cast<float4*>(C + (size_t)m*ldc + n0 + tn*4) = o4;
    }
}

// one doubling level: fill H[mc..min(2mc,Lw)) = H[0..]*Apow^T ; square Apow
__global__ void __launch_bounds__(256) k_hlevel(float* __restrict__ Hbuf,
                                                float* __restrict__ apow,
                                                int par, int mc) {
    int s = blockIdx.z;
    int Lw = d_Lw(s);
    const float* Asrc = apow + (size_t)par*196608 + (size_t)s*65536;
    float* Adst       = apow + (size_t)(1-par)*196608 + (size_t)s*65536;
    float* H = Hbuf + d_Hoff(s);
    int yt = blockIdx.y, xt = blockIdx.x;
    if (yt < 4) {
        if (mc >= Lw) return;
        int rows = min(mc, Lw - mc);
        if (yt*64 >= rows) return;
        gemm64nt(H, 256, rows, Asrc, 256, H + (size_t)mc*256, 256,
                 yt*64, xt*64, 256);
    } else {
        if (2*mc >= Lw) return;
        gemm64nn(Asrc, 256, Asrc, 256, Adst, 256, (yt-4)*64, xt*64, 256);
    }
}

// transpose H (Lw x 256) -> HT (256 x Lw), per scale
__global__ void k_htr(const float* __restrict__ Hbuf, float* __restrict__ HT) {
    int i = blockIdx.x*256 + threadIdx.x;
    if (i >= 344064) return;
    int s, rem;
    if (i < 49152)       { s=0; rem=i; }
    else if (i < 147456) { s=1; rem=i-49152; }
    else                 { s=2; rem=i-147456; }
    int Lw = d_Lw(s);
    int k = rem / Lw, m = rem - k*Lw;
    HT[i] = Hbuf[d_Hoff(s) + (size_t)m*256 + k];
}

// Call (Lw x 16384) = HT^T (Lw x 256) * Bpack (256 x 16384), Bpack virtual.
// 128x128 tiles, 8x8 acc, DOUBLE-BUFFERED LDS (1 barrier/k-step).
// Epilogue ALSO computes this m-tile's scan-chunk partial:
//   psum[cg][o][k] = sum_{m in tile} tw[m,k] * C[m,k,o]   (complex)
__global__ void __launch_bounds__(256) k_cgemm(
    const float* __restrict__ HT, const float* __restrict__ wrS,
    const float* __restrict__ wiS, const float2* __restrict__ tws,
    float2* __restrict__ psum, float* __restrict__ C, int Lw, int cgbase)
{
    int m0 = blockIdx.x*128, n0 = blockIdx.y*128;
    __shared__ __align__(16) float sm[8448];   // A0|A1|B0|B1, each 16*132
    int tid = threadIdx.x;
    int ty = tid >> 4, tx = tid & 15;
    int lq = tid >> 5;           // 0..7
    int lc = (tid & 31) * 4;     // 0..124
    const float* Ap0 = HT + (size_t)lq*Lw + m0 + lc;
    const float* Ap1 = HT + (size_t)(lq+8)*Lw + m0 + lc;
    int o  = (n0 + lc) >> 6;
    int kb = (lc & 63) >> 1;
    const float* wr0 = wrS + (size_t)lq*8192 + (size_t)o*32 + kb;
    const float* wi0 = wiS + (size_t)lq*8192 + (size_t)o*32 + kb;
    float4 fa0 = ldg4(Ap0), fa1 = ldg4(Ap1);
    float2 r0 = ldg2(wr0),           i0 = ldg2(wi0);
    float2 r1 = ldg2(wr0 + 8*8192),  i1 = ldg2(wi0 + 8*8192);
    // stage buffer 0
    {
        float* As0 = sm;            float* Bs0 = sm + 4224;
        *reinterpret_cast<float4*>(&As0[lq*132+lc])     = fa0;
        *reinterpret_cast<float4*>(&As0[(lq+8)*132+lc]) = fa1;
        *reinterpret_cast<float4*>(&Bs0[lq*132+lc])     = make_float4(r0.x, i0.x, r0.y, i0.y);
        *reinterpret_cast<float4*>(&Bs0[(lq+8)*132+lc]) = make_float4(r1.x, i1.x, r1.y, i1.y);
    }
    vf2 acc[8][4] = {};
    int cur = 0;
    for (int kt = 0; kt < 256; kt += 16) {
        __syncthreads();
        bool pf = (kt + 16) < 256;
        if (pf) {
            fa0 = ldg4(Ap0 + (size_t)(kt+16)*Lw);
            fa1 = ldg4(Ap1 + (size_t)(kt+16)*Lw);
            r0 = ldg2(wr0 + (size_t)(kt+16)*8192);
            i0 = ldg2(wi0 + (size_t)(kt+16)*8192);
            r1 = ldg2(wr0 + (size_t)(kt+24)*8192);
            i1 = ldg2(wi0 + (size_t)(kt+24)*8192);
        }
        const float* Asc = sm + cur*2112;
        const float* Bsc = sm + 4224 + cur*2112;
        #pragma unroll
        for (int q = 0; q < 16; q++) {
            F4V2 ua0, ua1, ub0, ub1;
            ua0.f4 = *reinterpret_cast<const float4*>(&Asc[q*132 + ty*8]);
            ua1.f4 = *reinterpret_cast<const float4*>(&Asc[q*132 + ty*8 + 4]);
            ub0.f4 = *reinterpret_cast<const float4*>(&Bsc[q*132 + tx*4]);
            ub1.f4 = *reinterpret_cast<const float4*>(&Bsc[q*132 + 64 + tx*4]);
            vf2 apair[4] = {ua0.v2[0], ua0.v2[1], ua1.v2[0], ua1.v2[1]};
            vf2 bpair[4] = {ub0.v2[0], ub0.v2[1], ub1.v2[0], ub1.v2[1]};
            #pragma unroll
            for (int ra = 0; ra < 4; ra++)
                #pragma unroll
                for (int cp = 0; cp < 4; cp++) {
                    pklo(acc[2*ra+0][cp], apair[ra], bpair[cp]);
                    pkhi(acc[2*ra+1][cp], apair[ra], bpair[cp]);
                }
        }
        if (pf) {
            int nxt = cur ^ 1;
            float* Asn = sm + nxt*2112;
            float* Bsn = sm + 4224 + nxt*2112;
            *reinterpret_cast<float4*>(&Asn[lq*132+lc])     = fa0;
            *reinterpret_cast<float4*>(&Asn[(lq+8)*132+lc]) = fa1;
            *reinterpret_cast<float4*>(&Bsn[lq*132+lc])     = make_float4(r0.x, i0.x, r0.y, i0.y);
            *reinterpret_cast<float4*>(&Bsn[(lq+8)*132+lc]) = make_float4(r1.x, i1.x, r1.y, i1.y);
            cur = nxt;
        }
    }
    // ---- C store + scan-chunk partial ----
    // acc[r][0]=(o0,k0) complex; [1]=(o0,k1); [2]=(o1,k0); [3]=(o1,k1)
    int k0 = tx*2;
    float2 pj[4] = {{0.f,0.f},{0.f,0.f},{0.f,0.f},{0.f,0.f}};
    #pragma unroll
    for (int r = 0; r < 8; r++) {
        int row = m0 + ty*8 + r;
        if (row < Lw) {
            float* p = C + (size_t)row*16384 + n0 + tx*4;
            *reinterpret_cast<float4*>(p)    = make_float4(acc[r][0].x, acc[r][0].y, acc[r][1].x, acc[r][1].y);
            *reinterpret_cast<float4*>(p+64) = make_float4(acc[r][2].x, acc[r][2].y, acc[r][3].x, acc[r][3].y);
            float2 t0 = tws[row*32 + k0];
            float2 t1 = tws[row*32 + k0 + 1];
            pj[0].x = fmaf(t0.x, acc[r][0].x, pj[0].x); pj[0].x = fmaf(-t0.y, acc[r][0].y, pj[0].x);
            pj[0].y = fmaf(t0.x, acc[r][0].y, pj[0].y); pj[0].y = fmaf( t0.y, acc[r][0].x, pj[0].y);
            pj[1].x = fmaf(t1.x, acc[r][1].x, pj[1].x); pj[1].x = fmaf(-t1.y, acc[r][1].y, pj[1].x);
            pj[1].y = fmaf(t1.x, acc[r][1].y, pj[1].y); pj[1].y = fmaf( t1.y, acc[r][1].x, pj[1].y);
            pj[2].x = fmaf(t0.x, acc[r][2].x, pj[2].x); pj[2].x = fmaf(-t0.y, acc[r][2].y, pj[2].x);
            pj[2].y = fmaf(t0.x, acc[r][2].y, pj[2].y); pj[2].y = fmaf( t0.y, acc[r][2].x, pj[2].y);
            pj[3].x = fmaf(t1.x, acc[r][3].x, pj[3].x); pj[3].x = fmaf(-t1.y, acc[r][3].y, pj[3].x);
            pj[3].y = fmaf(t1.x, acc[r][3].y, pj[3].y); pj[3].y = fmaf( t1.y, acc[r][3].x, pj[3].y);
        }
    }
    __syncthreads();              // all compute reads done; sm reusable
    float2* red = (float2*)sm;    // 256 threads x 4 float2 = 8 KB
    #pragma unroll
    for (int q = 0; q < 4; q++) red[tid*4+q] = pj[q];
    __syncthreads();
    #pragma unroll
    for (int st = 8; st >= 1; st >>= 1) {
        if (ty < st) {
            #pragma unroll
            for (int q = 0; q < 4; q++) {
                float2 a = red[tid*4+q];
                float2 b = red[((ty+st)*16+tx)*4+q];
                a.x += b.x; a.y += b.y;
                red[tid*4+q] = a;
            }
        }
        __syncthreads();
    }
    if (ty == 0) {
        int o0 = blockIdx.y*2;
        size_t cg = (size_t)(cgbase + blockIdx.x);
        psum[cg*8192 + (size_t)o0*32 + k0]       = red[tx*4+0];
        psum[cg*8192 + (size_t)o0*32 + k0 + 1]   = red[tx*4+1];
        psum[cg*8192 + (size_t)(o0+1)*32 + k0]   = red[tx*4+2];
        psum[cg*8192 + (size_t)(o0+1)*32 + k0+1] = red[tx*4+3];
    }
}

// prefix chunks (CH=128, aligned with cgemm m-tiles), rescan, contract over k
__global__ void k_cscan2(const float2* __restrict__ Call2, const float2* __restrict__ twm,
                         const float2* __restrict__ gtm, const float2* __restrict__ psum,
                         float* __restrict__ Qrow, int s, int cgbase, int Lw) {
    int cl = blockIdx.x;
    int tid = threadIdx.x;
    int k = tid & 31, ol = tid >> 5;
    int o = blockIdx.y*8 + ol;
    const float2* tws = twm + d_twoff(s);
    const float2* gts = gtm + d_twoff(s);
    float pr = 0.f, pi = 0.f;
    for (int c = 0; c < cl; c++) {
        float2 p = psum[((size_t)(cgbase+c))*8192 + o*32 + k];
        pr += p.x; pi += p.y;
    }
    int mbase = cl*128;
    int mend = min(128, Lw - mbase);
    for (int mm = 0; mm < mend; mm++) {
        int m = mbase + mm;
        float2 cc = Call2[(size_t)m*8192 + o*32 + k];
        float2 t  = tws[(size_t)m*32 + k];
        pr = fmaf(t.x, cc.x, pr); pr = fmaf(-t.y, cc.y, pr);
        pi = fmaf(t.x, cc.y, pi); pi = fmaf(t.y, cc.x, pi);
        int r = Lw - 1 - m;
        float2 g = gts[(size_t)r*32 + k];
        float qv = g.x*pr - g.y*pi;
        qv += __shfl_xor(qv, 16);
        qv += __shfl_xor(qv, 8);
        qv += __shfl_xor(qv, 4);
        qv += __shfl_xor(qv, 2);
        qv += __shfl_xor(qv, 1);
        if (k == 0) Qrow[(size_t)r*256 + o] = qv;
    }
}

// T[r,p] = sum_o Q[r,o] * Esub[p,o]   (batched over all scales)
__global__ void __launch_bounds__(256) k_tgemm(const float* __restrict__ Qall,
                                               const float* __restrict__ E0,
                                               const float* __restrict__ E1,
                                               const float* __restrict__ E2,
                                               float* __restrict__ T) {
    int mtg = blockIdx.x;
    int s, lm, Lw, rowoff, Toff;
    if (mtg < 3)      { s=0; lm=mtg;   Lw=192; rowoff=0;   Toff=0; }
    else if (mtg < 9) { s=1; lm=mtg-3; Lw=384; rowoff=192; Toff=36864; }
    else              { s=2; lm=mtg-9; Lw=768; rowoff=576; Toff=110592; }
    const float* Es = (s==0) ? E0 : ((s==1) ? E1 : E2);
    gemm64nt(Qall + (size_t)rowoff*256, 256, Lw,
             Es + (size_t)(Lw-192)*256, 256,
             T + Toff, 192, lm*64, blockIdx.y*64, 256);
}

// Mtot[p,t] = sum_i mw[i] * T_i[t-off_i, p]
__global__ void k_mtot(const float* __restrict__ T, const float* __restrict__ mlpw,
                       float* __restrict__ M) {
    int i = blockIdx.x*256 + threadIdx.x;
    if (i >= 192*768) return;
    int p = i / 768, t = i % 768;
    float v = mlpw[2] * T[110592 + (size_t)t*192 + p];
    if (t >= 384) v += mlpw[1] * T[36864 + (size_t)(t-384)*192 + p];
    if (t >= 576) v += mlpw[0] * T[(size_t)(t-576)*192 + p];
    M[i] = v;
}

// out[b,p,j]: each thread computes 4 p's for one output column cc.
__global__ void __launch_bounds__(256) k_final2(
    const float* __restrict__ M, const float* __restrict__ xn,
    const float* __restrict__ aw, const float* __restrict__ ab,
    const float* __restrict__ meanb, const float* __restrict__ stdb,
    const float* __restrict__ mlpb, float* __restrict__ out)
{
    __shared__ float Ms[4*768];
    int tid = threadIdx.x;
    int pg = blockIdx.y;
    #pragma unroll
    for (int e = tid; e < 3072; e += 256)
        Ms[e] = M[(size_t)pg*3072 + e];
    __syncthreads();
    int cc = blockIdx.x*256 + tid;
    if (cc >= BE) return;
    int b = (cc >= ENC) ? 1 : 0;
    int j = cc - b*ENC;
    const float* xp = xn + (size_t)b*SEQ*ENC + j;
    float a0 = 0.f, a1 = 0.f, a2 = 0.f, a3 = 0.f;
    #pragma unroll 4
    for (int t = 0; t < 768; t++) {
        float xv = xp[(size_t)t*ENC];
        a0 = fmaf(Ms[t],        xv, a0);
        a1 = fmaf(Ms[768 + t],  xv, a1);
        a2 = fmaf(Ms[1536 + t], xv, a2);
        a3 = fmaf(Ms[2304 + t], xv, a3);
    }
    float mb = mlpb[0];
    float inv = 1.f / (aw[j] + 1e-10f);
    float sd = stdb[b*ENC + j], mn = meanb[b*ENC + j], abj = ab[j];
    float acc4[4] = {a0, a1, a2, a3};
    #pragma unroll
    for (int u = 0; u < 4; u++) {
        int p = pg*4 + u;
        float v = (acc4[u] + mb - abj) * inv * sd + mn;
        out[(size_t)b*(PRED*ENC) + (size_t)p*ENC + j] = v;
    }
}

// ------------------------------------------------------------------
extern "C" void kernel_launch(void* const* d_in, const int* in_sizes, int n_in,
                              void* d_out, int out_size, void* d_ws, size_t ws_size,
                              hipStream_t stream)
{
    const float* hist = (const float*)d_in[0];
    const float* aw   = (const float*)d_in[2];
    const float* ab   = (const float*)d_in[3];
    const float* Ast  = (const float*)d_in[4];
    const float* Bst  = (const float*)d_in[5];
    const float* E0   = (const float*)d_in[6];
    const float* E1   = (const float*)d_in[7];
    const float* E2   = (const float*)d_in[8];
    const float* wr   = (const float*)d_in[9];
    const float* wi   = (const float*)d_in[10];
    const float* mlpw = (const float*)d_in[11];
    const float* mlpb = (const float*)d_in[12];
    float* out = (float*)d_out;

    float* w = (float*)d_ws;
    float* xn    = w; w += 493056;
    float* meanb = w; w += 642;
    float* stdb  = w; w += 642;
    float* Hbuf  = w; w += 344064;
    float* HT    = w; w += 344064;
    float* apow  = w; w += 393216;
    float2* twm  = (float2*)w; w += 86016;
    float2* gtm  = (float2*)w; w += 86016;
    float2* psum = (float2*)w; w += 180224;   // 11 chunks x 8192 float2
    float* Call  = w; w += 12582912;          // up to 768 x 16384 (per scale, reused)
    float* Qall  = w; w += 344064;            // 1344 x 256
    float* Tbuf  = w; w += 258048;
    float* Mt    = w; w += 147456;
    // total ~15.2M floats = 61 MB (< 78 MB proven)

    k_stats<<<dim3(6,2), dim3(64,4), 0, stream>>>(hist, meanb, stdb);
    k_norm<<<1926, 256, 0, stream>>>(hist, meanb, stdb, aw, ab, xn);
    k_tw<<<168, 256, 0, stream>>>(twm, gtm);
    k_hinit<<<768, 256, 0, stream>>>(Ast, Bst, apow, Hbuf);
    for (int lev = 0; lev < 10; lev++)
        k_hlevel<<<dim3(4,8,3), 256, 0, stream>>>(Hbuf, apow, lev & 1, 1 << lev);
    k_htr<<<1344, 256, 0, stream>>>(Hbuf, HT);

    const int Lws[3]    = {192, 384, 768};
    const int cgbase[3] = {0, 2, 5};
    const int rowoff[3] = {0, 192, 576};
    for (int s = 0; s < 3; s++) {
        int Lw = Lws[s];
        int mt = (Lw + 127) / 128;
        k_cgemm<<<dim3(mt, 128), 256, 0, stream>>>(HT + d_Hoff(s),
                                                   wr + (size_t)s*2097152,
                                                   wi + (size_t)s*2097152,
                                                   twm + d_twoff(s), psum,
                                                   Call, Lw, cgbase[s]);
        k_cscan2<<<dim3(mt, 32), 256, 0, stream>>>((const float2*)Call, twm, gtm, psum,
                                                   Qall + (size_t)rowoff[s]*256, s, cgbase[s], Lw);
    }
    k_tgemm<<<dim3(21,3), 256, 0, stream>>>(Qall, E0, E1, E2, Tbuf);
    k_mtot<<<576, 256, 0, stream>>>(Tbuf, mlpw, Mt);
    k_final2<<<dim3(3, 48), 256, 0, stream>>>(Mt, xn, aw, ab, meanb, stdb, mlpb, out);
}